// Round 5
// baseline (49.747 us; speedup 1.0000x reference)
//
#include <hip/hip_runtime.h>

// HierarchicalLayerNorm: B=8, S=4096, D=1024, fp32.
// Per-token LayerNorm (eps=1e-6, biased var), then per-token affine from:
//   assign in [0,19] -> splat_{w,b}[min(assign,7)]; assign==20 -> base_{w,b}.
//
// Memory-bound: 128 MiB in + 128 MiB out, zero reuse -> stream x/out with
// nontemporal loads/stores (bypass cache allocation; working set == L3 size).
// One wave per row (D=1024 -> 16 floats/lane), shuffle-only reduction,
// two-pass variance from registers. Gamma/beta tables (~72 KB) stay cached.
//
// NOTE: __builtin_nontemporal_* requires a clang ext_vector type, not HIP's
// struct-based float4 -- use f32x4 below.

#define HLN_B 8
#define HLN_S 4096
#define HLN_D 1024
#define HLN_NUM_SPLATS 20
#define HLN_NUM_SPLAT_NORMS 8
#define HLN_EPS 1e-6f

#define ROWS_PER_BLOCK 4   // 4 waves * 64 lanes = 256 threads

typedef float f32x4 __attribute__((ext_vector_type(4)));

__global__ __launch_bounds__(256) void HierarchicalLayerNorm_38431367364877_kernel(
    const float* __restrict__ x,
    const int*   __restrict__ splat_assign,
    const float* __restrict__ splat_w,
    const float* __restrict__ splat_b,
    const float* __restrict__ base_w,
    const float* __restrict__ base_b,
    float*       __restrict__ out)
{
    const int wave = threadIdx.x >> 6;          // 0..3
    const int lane = threadIdx.x & 63;          // 0..63
    const int row  = blockIdx.x * ROWS_PER_BLOCK + wave;   // grid sized exactly

    const float* xr = x + (size_t)row * HLN_D;

    // Each lane: 4x f32x4 = 16 floats, streamed (read-once) -> nontemporal.
    f32x4 v[4];
    #pragma unroll
    for (int k = 0; k < 4; ++k) {
        v[k] = __builtin_nontemporal_load(
            reinterpret_cast<const f32x4*>(xr + (lane + k * 64) * 4));
    }

    // Pass 1: mean
    float s = 0.0f;
    #pragma unroll
    for (int k = 0; k < 4; ++k) s += (v[k].x + v[k].y) + (v[k].z + v[k].w);
    #pragma unroll
    for (int off = 32; off >= 1; off >>= 1) s += __shfl_xor(s, off, 64);
    const float mean = s * (1.0f / HLN_D);

    // Pass 2: biased variance of (x - mean), from registers (matches reference numerics)
    float q = 0.0f;
    #pragma unroll
    for (int k = 0; k < 4; ++k) {
        float a = v[k].x - mean, b = v[k].y - mean;
        float c = v[k].z - mean, d = v[k].w - mean;
        q += (a * a + b * b) + (c * c + d * d);
    }
    #pragma unroll
    for (int off = 32; off >= 1; off >>= 1) q += __shfl_xor(q, off, 64);
    const float inv = rsqrtf(q * (1.0f / HLN_D) + HLN_EPS);

    // Wave-uniform affine-table selection (tables are L1/L2-resident, ~72 KB total)
    const int a = splat_assign[row];
    const float* wrow;
    const float* brow;
    if (a >= HLN_NUM_SPLATS) {
        wrow = base_w;
        brow = base_b;
    } else {
        const int idx = a < (HLN_NUM_SPLAT_NORMS - 1) ? a : (HLN_NUM_SPLAT_NORMS - 1);
        wrow = splat_w + (size_t)idx * HLN_D;
        brow = splat_b + (size_t)idx * HLN_D;
    }

    float* orow = out + (size_t)row * HLN_D;
    #pragma unroll
    for (int k = 0; k < 4; ++k) {
        const int off = (lane + k * 64) * 4;
        const f32x4 g  = *reinterpret_cast<const f32x4*>(wrow + off);
        const f32x4 be = *reinterpret_cast<const f32x4*>(brow + off);
        f32x4 r;
        r.x = (v[k].x - mean) * inv * g.x + be.x;
        r.y = (v[k].y - mean) * inv * g.y + be.y;
        r.z = (v[k].z - mean) * inv * g.z + be.z;
        r.w = (v[k].w - mean) * inv * g.w + be.w;
        __builtin_nontemporal_store(r, reinterpret_cast<f32x4*>(orow + off));
    }
}

extern "C" void kernel_launch(void* const* d_in, const int* in_sizes, int n_in,
                              void* d_out, int out_size, void* d_ws, size_t ws_size,
                              hipStream_t stream) {
    const float* x            = (const float*)d_in[0];
    const int*   splat_assign = (const int*)  d_in[1];
    const float* splat_w      = (const float*)d_in[2];
    const float* splat_b      = (const float*)d_in[3];
    const float* base_w       = (const float*)d_in[4];
    const float* base_b       = (const float*)d_in[5];
    float*       out          = (float*)d_out;

    const int rows = HLN_B * HLN_S;                 // 32768
    const int grid = rows / ROWS_PER_BLOCK;         // 8192 blocks of 256 threads

    HierarchicalLayerNorm_38431367364877_kernel<<<grid, 256, 0, stream>>>(
        x, splat_assign, splat_w, splat_b, base_w, base_b, out);
}

// Round 6
// 45.841 us; speedup vs baseline: 1.0852x; 1.0852x over previous
//
#include <hip/hip_runtime.h>

// HierarchicalLayerNorm: B=8, S=4096, D=1024, fp32.
// Per-token LayerNorm (eps=1e-6, biased var), then per-token affine from:
//   assign in [0,19] -> splat_{w,b}[min(assign,7)]; assign==20 -> base_{w,b}.
//
// Memory-bound: 128 MiB in + 128 MiB out. One wave per row (D=1024 -> 16
// floats/lane), shuffle-only reduction, two-pass variance from registers.
//
// R4 post-mortem: __builtin_nontemporal_* on the streamed tensors REGRESSED
// 46.1 -> 49.7 us (nt demotes L2/L3 path; partial L3 residency across replays
// is worth more than avoided eviction). Plain cached loads/stores are best:
// 46.07 us = 5.83 TB/s = 92.7% of the 6.29 TB/s measured D2D-copy ceiling.

#define HLN_B 8
#define HLN_S 4096
#define HLN_D 1024
#define HLN_NUM_SPLATS 20
#define HLN_NUM_SPLAT_NORMS 8
#define HLN_EPS 1e-6f

#define ROWS_PER_BLOCK 4   // 4 waves * 64 lanes = 256 threads

__global__ __launch_bounds__(256) void HierarchicalLayerNorm_38431367364877_kernel(
    const float* __restrict__ x,
    const int*   __restrict__ splat_assign,
    const float* __restrict__ splat_w,
    const float* __restrict__ splat_b,
    const float* __restrict__ base_w,
    const float* __restrict__ base_b,
    float*       __restrict__ out)
{
    const int wave = threadIdx.x >> 6;          // 0..3
    const int lane = threadIdx.x & 63;          // 0..63
    const int row  = blockIdx.x * ROWS_PER_BLOCK + wave;   // grid sized exactly

    const float* xr = x + (size_t)row * HLN_D;

    // Each lane: 4x float4 = 16 floats. Lane l, chunk k -> elems (l + k*64)*4 ..+3
    float4 v[4];
    #pragma unroll
    for (int k = 0; k < 4; ++k) {
        v[k] = *reinterpret_cast<const float4*>(xr + (lane + k * 64) * 4);
    }

    // Pass 1: mean
    float s = 0.0f;
    #pragma unroll
    for (int k = 0; k < 4; ++k) s += (v[k].x + v[k].y) + (v[k].z + v[k].w);
    #pragma unroll
    for (int off = 32; off >= 1; off >>= 1) s += __shfl_xor(s, off, 64);
    const float mean = s * (1.0f / HLN_D);

    // Pass 2: biased variance of (x - mean), from registers (matches reference numerics)
    float q = 0.0f;
    #pragma unroll
    for (int k = 0; k < 4; ++k) {
        float a = v[k].x - mean, b = v[k].y - mean;
        float c = v[k].z - mean, d = v[k].w - mean;
        q += (a * a + b * b) + (c * c + d * d);
    }
    #pragma unroll
    for (int off = 32; off >= 1; off >>= 1) q += __shfl_xor(q, off, 64);
    const float inv = rsqrtf(q * (1.0f / HLN_D) + HLN_EPS);

    // Wave-uniform affine-table selection (tables are L1/L2-resident, ~72 KB total)
    const int a = splat_assign[row];
    const float* wrow;
    const float* brow;
    if (a >= HLN_NUM_SPLATS) {
        wrow = base_w;
        brow = base_b;
    } else {
        const int idx = a < (HLN_NUM_SPLAT_NORMS - 1) ? a : (HLN_NUM_SPLAT_NORMS - 1);
        wrow = splat_w + (size_t)idx * HLN_D;
        brow = splat_b + (size_t)idx * HLN_D;
    }

    float* orow = out + (size_t)row * HLN_D;
    #pragma unroll
    for (int k = 0; k < 4; ++k) {
        const int off = (lane + k * 64) * 4;
        const float4 g  = *reinterpret_cast<const float4*>(wrow + off);
        const float4 be = *reinterpret_cast<const float4*>(brow + off);
        float4 r;
        r.x = (v[k].x - mean) * inv * g.x + be.x;
        r.y = (v[k].y - mean) * inv * g.y + be.y;
        r.z = (v[k].z - mean) * inv * g.z + be.z;
        r.w = (v[k].w - mean) * inv * g.w + be.w;
        *reinterpret_cast<float4*>(orow + off) = r;
    }
}

extern "C" void kernel_launch(void* const* d_in, const int* in_sizes, int n_in,
                              void* d_out, int out_size, void* d_ws, size_t ws_size,
                              hipStream_t stream) {
    const float* x            = (const float*)d_in[0];
    const int*   splat_assign = (const int*)  d_in[1];
    const float* splat_w      = (const float*)d_in[2];
    const float* splat_b      = (const float*)d_in[3];
    const float* base_w       = (const float*)d_in[4];
    const float* base_b       = (const float*)d_in[5];
    float*       out          = (float*)d_out;

    const int rows = HLN_B * HLN_S;                 // 32768
    const int grid = rows / ROWS_PER_BLOCK;         // 8192 blocks of 256 threads

    HierarchicalLayerNorm_38431367364877_kernel<<<grid, 256, 0, stream>>>(
        x, splat_assign, splat_w, splat_b, base_w, base_b, out);
}